// Round 8
// baseline (383.394 us; speedup 1.0000x reference)
//
#include <hip/hip_runtime.h>

#define B_ 256
#define T_ 1024
#define V_ 5000
#define D_ 100
#define H_ 64
#define C_ 2

typedef float f32x4 __attribute__((ext_vector_type(4)));

#define SCALE_ 2.885390081777927f   // 2*log2(e): exp2(SCALE*x) == e^{2x}

// ---------------------------------------------------------------------------
// Kernel 1: EW[v][h] = 2*log2e*(sum_d E[v][d]*W[d][h] + b[h])   (unchanged)
// ---------------------------------------------------------------------------
__global__ __launch_bounds__(256) void ew_kernel(const float* __restrict__ E,
                                                 const float* __restrict__ W,
                                                 const float* __restrict__ bias,
                                                 float* __restrict__ EW) {
    int idx = blockIdx.x * 256 + threadIdx.x;   // 0 .. V_*H_
    if (idx >= V_ * H_) return;
    int h = idx & (H_ - 1);
    int v = idx >> 6;
    float acc = bias[h];
    const float* Erow = E + v * D_;
    #pragma unroll 4
    for (int d = 0; d < D_; ++d) {
        acc = fmaf(Erow[d], W[d * H_ + h], acc);
    }
    EW[idx] = SCALE_ * acc;
}

// ---------------------------------------------------------------------------
// Kernel 2: RNN. R12: SYSTOLIC ROTATION replaces the broadcast.
// R4-R11 post-mortem: LDS-b128 (666), paired readlane (623), grouped
// readlane (587 cyc/step) -- the step is ISSUE-bound on the broadcast class:
// 64 v_readlane at ~4.5cyc effective (crossbar+SGPR port) ~= 290 cyc/step.
// Fix: don't broadcast h[k] to all lanes; ROTATE h past the lanes with
// v_mov_dpp wave_ror1 (full-rate VALU). Lane j accumulates
// h[(j+dir*m)&63] * U[(j+dir*m)&63][j] as the state slides by one lane per
// micro-step. TWO 32-link chains (B starts at h[j^32] via one ds_bpermute;
// rotate-by-32 == xor32) break the serial-latency chain: each chain's next
// rotate is 4 insts after its predecessor -> DPP hazards covered, pure
// issue-bound: 62 mov_dpp + 64 fma + ~10 tail ~= 300-350 cyc/step.
// wave_ror direction convention is PROBED at init (rotate lane-id, read
// lane 0 -> dir in {1,63}); the U permutation uses (j + dir*m)&63, correct
// under either convention. uq register-pin kept (R7-verified).
// ---------------------------------------------------------------------------
#define ROT1(x) __int_as_float(__builtin_amdgcn_mov_dpp(                      \
                    __float_as_int(x), 0x13C /*wave_ror1*/, 0xF, 0xF, false))

__global__ __launch_bounds__(64, 1) void rnn_kernel(const int* __restrict__ tokens,
                                                    const float* __restrict__ EW,
                                                    const float* __restrict__ U,
                                                    const float* __restrict__ Wd,
                                                    const float* __restrict__ bd,
                                                    float* __restrict__ out) {
    const int b = blockIdx.x;     // batch element
    const int j = threadIdx.x;    // 0..63 : hidden unit

    __shared__ int sh_tok[T_ + 2];   // 4 KB + pad (kills tail guard)

    // --- probe wave_ror1 direction: dir=1 if lane j reads lane j+1, else 63
    int dir = __builtin_amdgcn_readfirstlane(
                  __builtin_amdgcn_mov_dpp(j, 0x13C, 0xF, 0xF, false));
    // (lane 0 reads lane 1 -> 1, or lane 63 -> 63; both handled below)

    // --- permuted (2*log2e)*U diagonals -> 16 float4 (64 VGPRs).
    // After m rotations lane j holds h[(j + dir*m)&63]; chain B starts
    // offset by 32. Load the matching U rows (init-only gather, L2-hit).
    f32x4 uqA[8], uqB[8];
    #pragma unroll
    for (int m = 0; m < 32; ++m) {
        int rowA = (j + dir * m) & 63;
        int rowB = (rowA + 32) & 63;
        uqA[m >> 2][m & 3] = SCALE_ * U[rowA * H_ + j];
        uqB[m >> 2][m & 3] = SCALE_ * U[rowB * H_ + j];
    }
    // SINGLE pin: all 64 values live in VGPRs at once (R7-verified pattern).
    asm volatile("" : "+v"(uqA[0]), "+v"(uqA[1]), "+v"(uqA[2]), "+v"(uqA[3]),
                      "+v"(uqA[4]), "+v"(uqA[5]), "+v"(uqA[6]), "+v"(uqA[7]),
                      "+v"(uqB[0]), "+v"(uqB[1]), "+v"(uqB[2]), "+v"(uqB[3]),
                      "+v"(uqB[4]), "+v"(uqB[5]), "+v"(uqB[6]), "+v"(uqB[7]));

    const int* tok = tokens + b * T_;
    #pragma unroll
    for (int k = 0; k < T_ / H_; ++k) {
        sh_tok[k * H_ + j] = tok[k * H_ + j];    // coalesced
    }
    if (j < 2) sh_tok[T_ + j] = 0;               // pad
    __syncthreads();

    const int x32a = (j ^ 32) << 2;   // ds_bpermute byte-addr for xor32

    float h = 0.f;
    float pooled = 0.f;

    // 2-step-deep xw prefetch pipeline (covers L2 latency of EW gather)
    int2 tkA = *(const int2*)&sh_tok[0];
    float xw0 = EW[tkA.x * H_ + j];
    float xw1 = EW[tkA.y * H_ + j];

    // one recurrence step: 2-chain systolic rotation, zero broadcasts
    #define RNN_STEP(tokv, xwv)                                          \
    {                                                                    \
        float r1 = h;                                                    \
        float r2 = __int_as_float(__builtin_amdgcn_ds_bpermute(          \
                       x32a, __float_as_int(h)));                        \
        float a0 = (xwv), a1 = 0.f;                                      \
        _Pragma("unroll")                                                \
        for (int l = 0; l < 31; ++l) {                                   \
            a0 = fmaf(r1, uqA[l >> 2][l & 3], a0);                       \
            r1 = ROT1(r1);                                               \
            a1 = fmaf(r2, uqB[l >> 2][l & 3], a1);                       \
            r2 = ROT1(r2);                                               \
        }                                                                \
        a0 = fmaf(r1, uqA[7][3], a0);                                    \
        a1 = fmaf(r2, uqB[7][3], a1);                                    \
        float x2 = a0 + a1;                                              \
        float ef = __builtin_amdgcn_exp2f(x2);                           \
        float r = __builtin_amdgcn_rcpf(ef + 1.f);                       \
        float hn = fmaf(-2.f, r, 1.f);                                   \
        h = ((tokv) != 0) ? hn : h;                                      \
        pooled += h;                                                     \
    }

    for (int t = 0; t < T_; t += 2) {
        // in-loop pin: any uq spill would force an in-loop reload.
        asm volatile("" :: "v"(uqA[0]), "v"(uqA[1]), "v"(uqA[2]), "v"(uqA[3]),
                           "v"(uqA[4]), "v"(uqA[5]), "v"(uqA[6]), "v"(uqA[7]),
                           "v"(uqB[0]), "v"(uqB[1]), "v"(uqB[2]), "v"(uqB[3]),
                           "v"(uqB[4]), "v"(uqB[5]), "v"(uqB[6]), "v"(uqB[7]));

        // prefetch steps t+2, t+3 (pad makes the tail read safe: EW[0])
        int2 tkB = *(const int2*)&sh_tok[t + 2];
        float xw2 = EW[tkB.x * H_ + j];
        float xw3 = EW[tkB.y * H_ + j];

        RNN_STEP(tkA.x, xw0);
        RNN_STEP(tkA.y, xw1);

        tkA = tkB;
        xw0 = xw2;
        xw1 = xw3;
    }
    #undef RNN_STEP

    // ---- epilogue: pooled mean -> dense(2) -> sigmoid ----
    float p = pooled * (1.0f / (float)T_);
    float v0 = p * Wd[j * C_ + 0];
    float v1 = p * Wd[j * C_ + 1];
    #pragma unroll
    for (int off = 32; off >= 1; off >>= 1) {
        v0 += __shfl_down(v0, off, 64);
        v1 += __shfl_down(v1, off, 64);
    }
    if (j == 0) {
        float l0 = v0 + bd[0];
        float l1 = v1 + bd[1];
        out[b * C_ + 0] = 1.f / (1.f + __expf(-l0));
        out[b * C_ + 1] = 1.f / (1.f + __expf(-l1));
    }
}

// ---------------------------------------------------------------------------
extern "C" void kernel_launch(void* const* d_in, const int* in_sizes, int n_in,
                              void* d_out, int out_size, void* d_ws, size_t ws_size,
                              hipStream_t stream) {
    const int*   tokens = (const int*)  d_in[0];  // [B,T] int32
    const float* E      = (const float*)d_in[1];  // [V,D]
    const float* W      = (const float*)d_in[2];  // [D,H]
    const float* U      = (const float*)d_in[3];  // [H,H]
    const float* bias   = (const float*)d_in[4];  // [H]
    const float* Wd     = (const float*)d_in[5];  // [H,C]
    const float* bd     = (const float*)d_in[6];  // [C]
    float* out = (float*)d_out;                   // [B,C]
    float* EW  = (float*)d_ws;                    // [V,H] scratch: 1.28 MB

    ew_kernel<<<(V_ * H_ + 255) / 256, 256, 0, stream>>>(E, W, bias, EW);
    rnn_kernel<<<B_, H_, 0, stream>>>(tokens, EW, U, Wd, bd, out);
}